// Round 6
// baseline (26.204 us; speedup 1.0000x reference)
//
#include <hip/hip_runtime.h>

#define NBATCH   32
#define NCH      64
#define NNODE    4096
#define WW       97

// fp32 value of np.linspace(-1,1,4)[2] (and -[1])
#define XNEG 0.33333334f

typedef float f32x4 __attribute__((ext_vector_type(4)));

__host__ __device__ constexpr float lag_rd(int j) {
  constexpr float X1 = -XNEG, X2 = XNEG;
  constexpr float D0 = (-1.0f - X1) * (-1.0f - X2) * (-2.0f);
  constexpr float D1 = (X1 + 1.0f) * (X1 - X2) * (X1 - 1.0f);
  constexpr float D2 = (X2 + 1.0f) * (X2 - X1) * (X2 - 1.0f);
  constexpr float D3 = 2.0f * (1.0f - X1) * (1.0f - X2);
  return j == 0 ? 1.0f / D0 : j == 1 ? 1.0f / D1 : j == 2 ? 1.0f / D2 : 1.0f / D3;
}

// ---- Kernel A: expand + prescale the shared weight table into d_ws ----
// wexp[c*32 + id] = { w[c][3id+j] * RDj }   (64*32 float4 = 32 KB)
__global__ __launch_bounds__(512)
void pw_expand_kernel(const float* __restrict__ w, f32x4* __restrict__ wexp) {
  const int r = blockIdx.x * 512 + threadIdx.x;   // [0, 2048)
  const int c = r >> 5, i = r & 31;
  const float* wr = w + c * WW + 3 * i;
  f32x4 v;
  v[0] = wr[0] * lag_rd(0);
  v[1] = wr[1] * lag_rd(1);
  v[2] = wr[2] * lag_rd(2);
  v[3] = wr[3] * lag_rd(3);
  wexp[r] = v;
}

// ---- Kernel B: barrier-free main body; thread owns c-quad x u-quad ----
__global__ __launch_bounds__(256, 4)
void pw_main_kernel(const float* __restrict__ x,
                    const f32x4* __restrict__ wexp_g,
                    float* __restrict__ out) {
  __shared__ f32x4 wexp[NCH * 32];   // 32 KB, only LDS use

  const int g   = blockIdx.x;
  const int b   = g >> 6;   // batch
  const int t   = g & 63;   // 64-wide nn block
  const int tid = threadIdx.x;

  // one-time wexp copy (only barrier in the kernel)
  #pragma unroll
  for (int k = 0; k < 8; ++k) wexp[tid + 256 * k] = wexp_g[tid + 256 * k];
  __syncthreads();

  const int l  = tid & 63;
  const int wv = tid >> 6;          // 0..3
  const int q  = l & 15;            // u-quad index
  const int a  = l >> 4;            // 0..3
  const int c0 = (wv << 4) + (a << 2);   // channel quad start (multiple of 4)
  const int u0 = q << 2;                 // nn-within-tile quad start

  // transposed source row x[b][t][*]; output (c,u) needs id of xrow[64u + c]
  const float* xrow = x + (((size_t)(b * NCH + t)) << 12);

  // 4 aligned f32x4: sources for u0+i, channels c0..c0+3 (full-line coalesced)
  f32x4 src[4];
  #pragma unroll
  for (int i = 0; i < 4; ++i)
    src[i] = *reinterpret_cast<const f32x4*>(xrow + ((u0 + i) << 6) + c0);

  // own x values: rows c0..c0+3, nn = 64t + u0..u0+3
  const size_t obase = (((size_t)(b * NCH + c0)) << 12) + ((size_t)(t << 6)) + u0;
  f32x4 own[4];
  #pragma unroll
  for (int j = 0; j < 4; ++j)
    own[j] = *reinterpret_cast<const f32x4*>(x + obase + ((size_t)j << 12));

  #pragma unroll
  for (int j = 0; j < 4; ++j) {
    const int c = c0 + j;
    f32x4 res;
    #pragma unroll
    for (int i = 0; i < 4; ++i) {
      // own bin id -> local coordinate (bitwise-identical to reference)
      const float xv = own[j][i];
      const float tt = (xv + 1.0f) * 16.0f;
      int idm = (int)tt;
      idm = idm < 0 ? 0 : (idm > 31 ? 31 : idm);
      const float xmin = fmaf((float)idm, 0.0625f, -1.0f);
      const float xin  = fmaf(xv - xmin, 32.0f, -1.0f);

      // transposed source -> weight window id (computed inline, no LDS table)
      const float sv = src[i][j];
      const float st = (sv + 1.0f) * 16.0f;
      int idw = (int)st;
      idw = idw < 0 ? 0 : (idw > 31 ? 31 : idw);
      const f32x4 w4 = wexp[(c << 5) + idw];

      const float t0  = xin + 1.0f;
      const float t1  = xin + XNEG;
      const float t2  = xin - XNEG;
      const float t3  = xin - 1.0f;
      const float u01 = t0 * t1, u23 = t2 * t3;
      const float p0  = t1 * u23;
      const float p1  = t0 * u23;
      const float p2  = u01 * t3;
      const float p3  = u01 * t2;

      res[i] = fmaf(p3, w4[3], fmaf(p2, w4[2], fmaf(p1, w4[1], p0 * w4[0])));
    }
    __builtin_nontemporal_store(res,
        reinterpret_cast<f32x4*>(out + obase + ((size_t)j << 12)));
  }
}

extern "C" void kernel_launch(void* const* d_in, const int* in_sizes, int n_in,
                              void* d_out, int out_size, void* d_ws, size_t ws_size,
                              hipStream_t stream) {
  const float* x = (const float*)d_in[0];
  const float* w = (const float*)d_in[1];
  float* out    = (float*)d_out;
  f32x4* wexp   = (f32x4*)d_ws;   // 32 KB scratch

  pw_expand_kernel<<<dim3(4), 512, 0, stream>>>(w, wexp);
  pw_main_kernel<<<dim3(NBATCH * (NNODE / 64)), 256, 0, stream>>>(x, wexp, out);
}

// Round 7
// 24.456 us; speedup vs baseline: 1.0715x; 1.0715x over previous
//
#include <hip/hip_runtime.h>

#define NBATCH   32
#define NCH      64
#define NNODE    4096
#define WW       97

typedef float     f32x4 __attribute__((ext_vector_type(4)));
typedef float     f32x2 __attribute__((ext_vector_type(2)));
typedef _Float16  h16x4 __attribute__((ext_vector_type(4)));

// ---- Kernel A: Lagrange window -> monomial (power-basis) f16 coeffs ----
// For nodes {-1,-1/3,1/3,1}: P(x) = sum_j w_j * N_j(x)/D_j  ==  a3 x^3 + a2 x^2 + a1 x + a0
// v = w .* {-9/16, 27/16, -27/16, 9/16}
// a3 =  v0 + v1 + v2 + v3
// a2 = -v0 - v1/3 + v2/3 + v3
// a1 = -v0/9 - v1 - v2 - v3/9
// a0 =  v0/9 + v1/3 - v2/3 - v3/9
__global__ __launch_bounds__(512)
void pw_expand_kernel(const float* __restrict__ w, h16x4* __restrict__ wexp) {
  const int r = blockIdx.x * 512 + threadIdx.x;   // [0, 2048)
  const int c = r >> 5, i = r & 31;
  const float* wr = w + c * WW + 3 * i;
  const float v0 = wr[0] * (-9.0f / 16.0f);
  const float v1 = wr[1] * (27.0f / 16.0f);
  const float v2 = wr[2] * (-27.0f / 16.0f);
  const float v3 = wr[3] * (9.0f / 16.0f);
  const float a3 = v0 + v1 + v2 + v3;
  const float a2 = -v0 - v1 * (1.0f / 3.0f) + v2 * (1.0f / 3.0f) + v3;
  const float a1 = -v0 * (1.0f / 9.0f) - v1 - v2 - v3 * (1.0f / 9.0f);
  const float a0 =  v0 * (1.0f / 9.0f) + v1 * (1.0f / 3.0f)
                  - v2 * (1.0f / 3.0f) - v3 * (1.0f / 9.0f);
  h16x4 h;
  h[0] = (_Float16)a0; h[1] = (_Float16)a1;
  h[2] = (_Float16)a2; h[3] = (_Float16)a3;
  wexp[r] = h;
}

// ---- Kernel B: barrier-free main body; thread owns c-pair x u-quad ----
__global__ __launch_bounds__(512, 8)
void pw_main_kernel(const float* __restrict__ x,
                    const h16x4* __restrict__ wexp_g,
                    float* __restrict__ out) {
  __shared__ h16x4 wexp[NCH * 32];   // 16 KB

  const int g   = blockIdx.x;
  // XCD-aware swizzle: all 64 WGs of a batch land on one XCD (1 MB slab -> L2-hot)
  const int xcd = g & 7;
  const int idx = g >> 3;                 // [0, 256)
  const int b   = ((idx >> 6) << 3) | xcd;
  const int t   = idx & 63;
  const int tid = threadIdx.x;

  // one-time 16 KB table copy (only barrier in the kernel)
  {
    const f32x4* s = reinterpret_cast<const f32x4*>(wexp_g);
    f32x4*       d = reinterpret_cast<f32x4*>(wexp);
    d[tid]       = s[tid];
    d[tid + 512] = s[tid + 512];
  }
  __syncthreads();

  const int l  = tid & 63;
  const int wv = tid >> 6;            // 0..7
  const int q  = l & 15;              // u-quad index
  const int a  = l >> 4;              // 0..3
  const int u0 = q << 2;
  const int c0 = (wv << 3) + (a << 1);   // even channel pair start

  // transposed source row x[b][t][*]; output (c,u) needs bin id of xrow[64u + c]
  const float* xrow = x + (((size_t)(b * NCH + t)) << 12);

  f32x2 src[4];
  #pragma unroll
  for (int i = 0; i < 4; ++i)
    src[i] = *reinterpret_cast<const f32x2*>(xrow + ((u0 + i) << 6) + c0);

  const size_t obase = (((size_t)(b * NCH + c0)) << 12) + ((size_t)(t << 6)) + u0;

  #pragma unroll
  for (int j = 0; j < 2; ++j) {
    const f32x4 own = *reinterpret_cast<const f32x4*>(x + obase + ((size_t)j << 12));
    const int cb = (c0 + j) << 5;
    f32x4 res;
    #pragma unroll
    for (int i = 0; i < 4; ++i) {
      // own bin id -> local coordinate  (ids bitwise-identical to reference)
      const float xv = own[i];
      const float tt = fmaf(xv, 16.0f, 16.0f);     // == (x+1)/2*32 bitwise
      int idm = (int)tt;                            // trunc toward zero
      idm = idm < 0 ? 0 : (idm > 31 ? 31 : idm);
      // xin = 32x - 2*idm + 31
      const float xin = fmaf(xv, 32.0f, fmaf((float)idm, -2.0f, 31.0f));

      // transposed element's bin id -> coefficient window (ds_read_b64)
      const float sv = src[i][j];
      const float st = fmaf(sv, 16.0f, 16.0f);
      int idw = (int)st;
      idw = idw < 0 ? 0 : (idw > 31 ? 31 : idw);
      const h16x4 hc = wexp[cb + idw];

      const float c0f = (float)hc[0], c1f = (float)hc[1];
      const float c2f = (float)hc[2], c3f = (float)hc[3];
      // Horner
      res[i] = fmaf(fmaf(fmaf(c3f, xin, c2f), xin, c1f), xin, c0f);
    }
    __builtin_nontemporal_store(res,
        reinterpret_cast<f32x4*>(out + obase + ((size_t)j << 12)));
  }
}

extern "C" void kernel_launch(void* const* d_in, const int* in_sizes, int n_in,
                              void* d_out, int out_size, void* d_ws, size_t ws_size,
                              hipStream_t stream) {
  const float* x = (const float*)d_in[0];
  const float* w = (const float*)d_in[1];
  float* out    = (float*)d_out;
  h16x4* wexp   = (h16x4*)d_ws;   // 16 KB scratch

  pw_expand_kernel<<<dim3(4), 512, 0, stream>>>(w, wexp);
  pw_main_kernel<<<dim3(NBATCH * (NNODE / 64)), 512, 0, stream>>>(x, wexp, out);
}

// Round 8
// 20.340 us; speedup vs baseline: 1.2883x; 1.2023x over previous
//
#include <hip/hip_runtime.h>

#define NBATCH   32
#define NCH      64
#define NNODE    4096
#define WW       97
#define NTHREADS 512

typedef float     f32x4 __attribute__((ext_vector_type(4)));
typedef float     f32x2 __attribute__((ext_vector_type(2)));
typedef _Float16  h16x4 __attribute__((ext_vector_type(4)));

// Single fused kernel.
// Grid: 2048 WGs; swizzle puts all 64 WGs of batch b on XCD b%8 so the
// transposed x re-read hits that XCD's L2 (WG(b,t) row-read reuses bytes
// own-read by WG(b,t') on the same XCD).
__global__ __launch_bounds__(NTHREADS)
void pw_kernel(const float* __restrict__ x,
               const float* __restrict__ w,
               float* __restrict__ out) {
  __shared__ h16x4 wexp[NCH * 32];   // 16 KB: monomial f16 coeffs per (c, id)

  const int g   = blockIdx.x;
  const int b   = (g & 7) | ((g >> 9) << 3);   // batch; XCD = g%8 = b%8
  const int t   = (g >> 3) & 63;               // 64-wide nn block
  const int tid = threadIdx.x;

  // ---- build monomial table from w (one-time per WG; w is L2-hot) ----
  // P(x) = sum_j w_j * L_j(x)  ->  a3 x^3 + a2 x^2 + a1 x + a0, nodes {-1,-1/3,1/3,1}
  #pragma unroll
  for (int k = 0; k < 4; ++k) {
    const int r = tid + k * NTHREADS;   // [0, 2048)
    const int c = r >> 5, i = r & 31;
    const float* wr = w + c * WW + 3 * i;
    const float v0 = wr[0] * (-9.0f / 16.0f);
    const float v1 = wr[1] * (27.0f / 16.0f);
    const float v2 = wr[2] * (-27.0f / 16.0f);
    const float v3 = wr[3] * (9.0f / 16.0f);
    const float a3 = v0 + v1 + v2 + v3;
    const float a2 = -v0 - v1 * (1.0f / 3.0f) + v2 * (1.0f / 3.0f) + v3;
    const float a1 = -v0 * (1.0f / 9.0f) - v1 - v2 - v3 * (1.0f / 9.0f);
    const float a0 =  v0 * (1.0f / 9.0f) + v1 * (1.0f / 3.0f)
                    - v2 * (1.0f / 3.0f) - v3 * (1.0f / 9.0f);
    h16x4 h;
    h[0] = (_Float16)a0; h[1] = (_Float16)a1;
    h[2] = (_Float16)a2; h[3] = (_Float16)a3;
    wexp[r] = h;
  }
  __syncthreads();

  const int l  = tid & 63;
  const int wv = tid >> 6;            // 0..7
  const int q  = l & 15;              // u-quad index
  const int a  = l >> 4;              // 0..3
  const int u0 = q << 2;
  const int c0 = (wv << 3) + (a << 1);   // even channel pair start

  // transposed source row x[b][t][*]; output (c,u) needs bin id of xrow[64u + c]
  const float* xrow = x + (((size_t)(b * NCH + t)) << 12);

  f32x2 src[4];
  #pragma unroll
  for (int i = 0; i < 4; ++i)
    src[i] = *reinterpret_cast<const f32x2*>(xrow + ((u0 + i) << 6) + c0);

  const size_t obase = (((size_t)(b * NCH + c0)) << 12) + ((size_t)(t << 6)) + u0;

  #pragma unroll
  for (int j = 0; j < 2; ++j) {
    const f32x4 own = *reinterpret_cast<const f32x4*>(x + obase + ((size_t)j << 12));
    const int cb = (c0 + j) << 5;
    f32x4 res;
    #pragma unroll
    for (int i = 0; i < 4; ++i) {
      // own bin id -> local coordinate (ids bitwise-identical to reference)
      const float xv = own[i];
      const float tt = fmaf(xv, 16.0f, 16.0f);     // == (x+1)/2*32 bitwise
      int idm = (int)tt;                            // trunc toward zero
      idm = idm < 0 ? 0 : (idm > 31 ? 31 : idm);
      // xin = 32x - 2*idm + 31
      const float xin = fmaf(xv, 32.0f, fmaf((float)idm, -2.0f, 31.0f));

      // transposed element's bin id -> coefficient window (ds_read_b64)
      const float sv = src[i][j];
      const float st = fmaf(sv, 16.0f, 16.0f);
      int idw = (int)st;
      idw = idw < 0 ? 0 : (idw > 31 ? 31 : idw);
      const h16x4 hc = wexp[cb + idw];

      const float c0f = (float)hc[0], c1f = (float)hc[1];
      const float c2f = (float)hc[2], c3f = (float)hc[3];
      res[i] = fmaf(fmaf(fmaf(c3f, xin, c2f), xin, c1f), xin, c0f);
    }
    __builtin_nontemporal_store(res,
        reinterpret_cast<f32x4*>(out + obase + ((size_t)j << 12)));
  }
}

extern "C" void kernel_launch(void* const* d_in, const int* in_sizes, int n_in,
                              void* d_out, int out_size, void* d_ws, size_t ws_size,
                              hipStream_t stream) {
  const float* x = (const float*)d_in[0];
  const float* w = (const float*)d_in[1];
  float* out    = (float*)d_out;
  pw_kernel<<<dim3(NBATCH * (NNODE / 64)), NTHREADS, 0, stream>>>(x, w, out);
}